// Round 5
// baseline (350.839 us; speedup 1.0000x reference)
//
#include <hip/hip_runtime.h>
#include <math.h>

#define TT 2048
#define HH 2048
#define NSTEP 16
#define EPSF 1e-8f
#define BETA 0.1f
#define TSPLIT 4
#define TCHUNK (TT / TSPLIT)                   // 512
#define NGROUP (TCHUNK / 8)                    // 64 groups of 8 rows
#define ROW2 (HH / 2)                          // 1024 float2 per row
#define PART_FLOATS ((size_t)64 * NSTEP * HH)  // floats per z-slice (8 MB)

// ---------------- Kernel 0: per-(b,n) stable counting sort of T by bucket ----------------
// 64 blocks x 64 threads (one wave). perm entry = (s<<11)|t packed u16.
__global__ __launch_bounds__(64) void k_sort(const int* __restrict__ step,
                                             unsigned short* __restrict__ perm) {
  const int bn   = blockIdx.x;
  const int lane = threadIdx.x;
  __shared__ int hist[NSTEP];
  volatile __shared__ int base[NSTEP];

  if (lane < NSTEP) hist[lane] = 0;
  __syncthreads();
  for (int t = lane; t < TT; t += 64) atomicAdd(&hist[step[bn * TT + t]], 1);
  __syncthreads();
  if (lane == 0) {
    int run = 0;
    for (int k = 0; k < NSTEP; ++k) { base[k] = run; run += hist[k]; }
  }
  __syncthreads();

  for (int it = 0; it < TT / 64; ++it) {
    const int t = it * 64 + lane;
    const int s = step[bn * TT + t];
#pragma unroll
    for (int k = 0; k < NSTEP; ++k) {
      const unsigned long long m = __ballot(s == k);
      const int bk = base[k];                      // all lanes read before update
      if (s == k) {
        const int r = (int)__popcll(m & ((1ull << lane) - 1ull));
        perm[bn * TT + bk + r] = (unsigned short)((k << 11) | t);
      }
      if (lane == 0) base[k] = bk + (int)__popcll(m);
      // single wave: program order + volatile keeps LDS coherent
    }
  }
}

// ---------------- Kernel 1: partial segment-sums over sorted rows ----------------
// grid (4, 64, TSPLIT), block 256. One float2 run-accumulator; flush on transition.
__global__ __launch_bounds__(256, 4) void k_segsum3(const float* __restrict__ hidden,
                                                    const unsigned short* __restrict__ perm,
                                                    float2* __restrict__ part) {
  const int bn   = blockIdx.y;
  const int z    = blockIdx.z;
  const int col2 = blockIdx.x * 256 + threadIdx.x;   // [0, 1024)
  const int t0   = z * TCHUNK;

  __shared__ unsigned s_perm[TCHUNK / 2];            // 256 packed words
  {
    const unsigned* gperm = (const unsigned*)(perm + (size_t)bn * TT + t0);
    s_perm[threadIdx.x] = gperm[threadIdx.x];
  }
  __syncthreads();

  const float2* hbase = (const float2*)hidden + (size_t)bn * TT * ROW2 + col2;
  float2* pb = (float2*)part + (size_t)z * (PART_FLOATS / 2) +
               ((size_t)bn * NSTEP) * ROW2 + col2;

  int sA[8], tA[8], sB[8], tB[8];
  float2 va[8], vb[8];
  int cur = -1;
  unsigned present = 0;
  float2 acc = make_float2(0.f, 0.f);

#define DECODE(SS, TI, g)                                                      \
  { const unsigned w0_ = (unsigned)__builtin_amdgcn_readfirstlane((int)s_perm[(g)*4+0]); \
    const unsigned w1_ = (unsigned)__builtin_amdgcn_readfirstlane((int)s_perm[(g)*4+1]); \
    const unsigned w2_ = (unsigned)__builtin_amdgcn_readfirstlane((int)s_perm[(g)*4+2]); \
    const unsigned w3_ = (unsigned)__builtin_amdgcn_readfirstlane((int)s_perm[(g)*4+3]); \
    SS[0]=(int)((w0_>>11)&15u); TI[0]=(int)(w0_&2047u);                        \
    SS[1]=(int)((w0_>>27)&15u); TI[1]=(int)((w0_>>16)&2047u);                  \
    SS[2]=(int)((w1_>>11)&15u); TI[2]=(int)(w1_&2047u);                        \
    SS[3]=(int)((w1_>>27)&15u); TI[3]=(int)((w1_>>16)&2047u);                  \
    SS[4]=(int)((w2_>>11)&15u); TI[4]=(int)(w2_&2047u);                        \
    SS[5]=(int)((w2_>>27)&15u); TI[5]=(int)((w2_>>16)&2047u);                  \
    SS[6]=(int)((w3_>>11)&15u); TI[6]=(int)(w3_&2047u);                        \
    SS[7]=(int)((w3_>>27)&15u); TI[7]=(int)((w3_>>16)&2047u); }

#define LOADG(dst, TI)                                           \
  _Pragma("unroll")                                              \
  for (int u = 0; u < 8; ++u) dst[u] = hbase[(size_t)TI[u] * ROW2];

#define PROCRUN(src, SS)                                                       \
  _Pragma("unroll")                                                            \
  for (int u = 0; u < 8; ++u) {                                                \
    if (SS[u] != cur) {                                                        \
      if (cur >= 0) { pb[(size_t)cur * ROW2] = acc; present |= (1u << cur); }  \
      acc.x = 0.f; acc.y = 0.f; cur = SS[u];                                   \
    }                                                                          \
    acc.x += src[u].x; acc.y += src[u].y;                                      \
  }

  DECODE(sA, tA, 0)
  LOADG(va, tA)
  for (int g = 0; g < NGROUP; g += 2) {
    DECODE(sB, tB, g + 1)
    LOADG(vb, tB)
    PROCRUN(va, sA)
    if (g + 2 < NGROUP) { DECODE(sA, tA, g + 2) LOADG(va, tA) }
    PROCRUN(vb, sB)
  }
#undef DECODE
#undef LOADG
#undef PROCRUN

  if (cur >= 0) { pb[(size_t)cur * ROW2] = acc; present |= (1u << cur); }
  const float2 z2 = make_float2(0.f, 0.f);
#pragma unroll
  for (int k = 0; k < NSTEP; ++k)
    if (!((present >> k) & 1u)) pb[(size_t)k * ROW2] = z2;
}

// ---------------- Kernel 1b: reduce TSPLIT partials -> ssum ----------------
__global__ __launch_bounds__(256) void k_reduce(const float4* __restrict__ part,
                                                float4* __restrict__ ssum) {
  const size_t i = (size_t)blockIdx.x * 256 + threadIdx.x;   // < PART_FLOATS/4
  const size_t slice = PART_FLOATS / 4;
  float4 s = part[i];
#pragma unroll
  for (int zz = 1; zz < TSPLIT; ++zz) {
    const float4 v = part[(size_t)zz * slice + i];
    s.x += v.x; s.y += v.y; s.z += v.z; s.w += v.w;
  }
  ssum[i] = s;
}

// ---------------- Kernel 2: per-(b,n) cosine weights -> text_logits ----------------
__global__ __launch_bounds__(1024) void k_bn(const float* __restrict__ pol,
                                             const float* __restrict__ refp,
                                             const int* __restrict__ step,
                                             const float* __restrict__ ssum,
                                             float* __restrict__ text_logits) {
  const int bn  = blockIdx.x;
  const int b   = bn >> 3;
  const int bn0 = b << 3;
  const int wave = threadIdx.x >> 6;   // 0..15 == segment
  const int lane = threadIdx.x & 63;

  __shared__ float cnt[NSTEP], cnt0[NSTEP], lsum[NSTEP], wgt[NSTEP];
  if (threadIdx.x < NSTEP) {
    cnt[threadIdx.x] = 0.f; cnt0[threadIdx.x] = 0.f; lsum[threadIdx.x] = 0.f;
  }
  __syncthreads();

  for (int t = threadIdx.x; t < TT; t += 1024) {
    const int s = step[bn * TT + t];
    atomicAdd(&cnt[s], 1.f);
    atomicAdd(&lsum[s], pol[bn * TT + t] - refp[bn * TT + t]);
    const int s0 = step[bn0 * TT + t];
    atomicAdd(&cnt0[s0], 1.f);
  }
  __syncthreads();

  const int s = wave;
  const float c  = fmaxf(cnt[s],  1.f);
  const float c0 = fmaxf(cnt0[s], 1.f);
  const float ic  = 1.f / c;
  const float ic0 = 1.f / c0;
  const float4* p  = (const float4*)(ssum + ((size_t)bn  * NSTEP + s) * HH);
  const float4* p0 = (const float4*)(ssum + ((size_t)bn0 * NSTEP + s) * HH);

  float dot = 0.f, nn = 0.f, rr = 0.f;
#pragma unroll
  for (int i = 0; i < 8; ++i) {
    const float4 a4 = p[lane + i * 64];
    const float4 r4 = p0[lane + i * 64];
    const float ax = a4.x * ic, ay = a4.y * ic, az = a4.z * ic, aw = a4.w * ic;
    const float rx = r4.x * ic0, ry = r4.y * ic0, rz = r4.z * ic0, rw = r4.w * ic0;
    dot += ax * rx + ay * ry + az * rz + aw * rw;
    nn  += ax * ax + ay * ay + az * az + aw * aw;
    rr  += rx * rx + ry * ry + rz * rz + rw * rw;
  }
#pragma unroll
  for (int off = 32; off > 0; off >>= 1) {
    dot += __shfl_down(dot, off);
    nn  += __shfl_down(nn,  off);
    rr  += __shfl_down(rr,  off);
  }
  if (lane == 0) {
    const float nrm = fmaxf(sqrtf(nn), EPSF);
    const float rn  = fmaxf(sqrtf(rr), EPSF);
    const float cosv = dot / (nrm * rn);
    const bool valid = (cnt[s] > 0.f) && (cnt0[s] > 0.f) && (s >= 1);
    wgt[s] = valid ? (cosv + 1.f) : 0.f;
  }
  __syncthreads();

  if (threadIdx.x == 0) {
    float wsum = 0.f, tw = 0.f;
#pragma unroll
    for (int k = 0; k < NSTEP; ++k) {
      const float w = wgt[k];
      wsum += w * (lsum[k] / fmaxf(cnt[k], 1.f));
      tw   += w;
    }
    text_logits[bn] = (tw > 0.f) ? (wsum / fmaxf(tw, EPSF)) : 0.f;
  }
}

// ---------------- Kernel 3: LambdaRank loss + reward means ----------------
__device__ inline float softplus_f(float x) {
  return fmaxf(x, 0.f) + log1pf(expf(-fabsf(x)));
}

__global__ __launch_bounds__(256) void k_final(const float* __restrict__ pol,
                                               const float* __restrict__ refp,
                                               const float* __restrict__ labels,
                                               const float* __restrict__ text_logits,
                                               float* __restrict__ out) {
  const int which = blockIdx.x;
  const int wave = threadIdx.x >> 6;
  const int lane = threadIdx.x & 63;
  __shared__ float red[4];

  if (which == 0) {
    float part = 0.f;
    if (threadIdx.x < 64) {
      const int b = threadIdx.x >> 3, i = threadIdx.x & 7;
      const float pi = text_logits[b * 8 + i];
      const float li = labels[b * 8 + i];
#pragma unroll
      for (int j = 0; j < 8; ++j) {
        const float ld = li - labels[b * 8 + j];
        const float sg = (ld > 0.f) ? 1.f : ((ld < 0.f) ? -1.f : 0.f);
        const float z  = (pi - text_logits[b * 8 + j]) * sg;
        part += softplus_f(-z);
      }
    }
    if (wave == 0) {
#pragma unroll
      for (int off = 32; off > 0; off >>= 1) part += __shfl_down(part, off);
      if (lane == 0) {
        const float lr = part / (56.f * 8.f);
        out[0] = softplus_f(-BETA * lr);
      }
    }
  } else {
    const int n = (which == 1) ? 0 : 7;
    float s = 0.f;
    for (int i = threadIdx.x; i < 8 * TT; i += 256) {
      const int b = i >> 11, t = i & (TT - 1);
      const size_t idx = ((size_t)(b * 8 + n)) * TT + t;
      s += pol[idx] - refp[idx];
    }
#pragma unroll
    for (int off = 32; off > 0; off >>= 1) s += __shfl_down(s, off);
    if (lane == 0) red[wave] = s;
    __syncthreads();
    if (threadIdx.x == 0)
      out[which] = (red[0] + red[1] + red[2] + red[3]) / (8.f * TT);
  }
}

extern "C" void kernel_launch(void* const* d_in, const int* in_sizes, int n_in,
                              void* d_out, int out_size, void* d_ws, size_t ws_size,
                              hipStream_t stream) {
  const float* pol    = (const float*)d_in[0];
  const float* refp   = (const float*)d_in[1];
  const float* hidden = (const float*)d_in[2];
  const int*   step   = (const int*)d_in[3];
  const float* labels = (const float*)d_in[4];
  float* out = (float*)d_out;

  float* part = (float*)d_ws;                                  // TSPLIT * 8 MB
  float* ssum = part + (size_t)TSPLIT * PART_FLOATS;           // 8 MB
  float* text_logits = ssum + PART_FLOATS;                     // 64 floats (+pad)
  unsigned short* perm = (unsigned short*)(text_logits + 256); // 256 KB

  k_sort<<<64, 64, 0, stream>>>(step, perm);
  dim3 g1(4, 64, TSPLIT);
  k_segsum3<<<g1, 256, 0, stream>>>(hidden, perm, (float2*)part);
  k_reduce<<<(int)(PART_FLOATS / 4 / 256), 256, 0, stream>>>((const float4*)part,
                                                             (float4*)ssum);
  k_bn<<<64, 1024, 0, stream>>>(pol, refp, step, ssum, text_logits);
  k_final<<<3, 256, 0, stream>>>(pol, refp, labels, text_logits, out);
}

// Round 6
// 251.295 us; speedup vs baseline: 1.3961x; 1.3961x over previous
//
#include <hip/hip_runtime.h>
#include <math.h>

#define TT 2048
#define HH 2048
#define NSTEP 16
#define EPSF 1e-8f
#define BETA 0.1f
#define TSPLIT 4
#define TCHUNK (TT / TSPLIT)                   // 512
#define ROW2 (HH / 2)                          // 1024 float2 per row
#define PART_FLOATS ((size_t)64 * NSTEP * HH)  // floats per z-slice (8 MB)

// ---------------- Kernel 1: partial segment-sums, float2, T-split ----------------
// grid (4, 64, TSPLIT), block 256. Sequential row order (DRAM-friendly).
// Step values prefetched one 8-row group ahead as uniform int4 LDS reads so the
// per-row chain is register-readfirstlane + compare tree only.
__global__ __launch_bounds__(256, 4) void k_segsum2(const float* __restrict__ hidden,
                                                    const int* __restrict__ step,
                                                    float2* __restrict__ part) {
  const int bn   = blockIdx.y;
  const int z    = blockIdx.z;
  const int col2 = blockIdx.x * 256 + threadIdx.x;   // [0, 1024)
  const int t0   = z * TCHUNK;

  __shared__ int s_step[TCHUNK];
  for (int i = threadIdx.x; i < TCHUNK; i += 256) s_step[i] = step[bn * TT + t0 + i];
  __syncthreads();

  const float2* hp = (const float2*)hidden + (size_t)(bn * TT + t0) * ROW2 + col2;

  float2 acc[NSTEP];
#pragma unroll
  for (int k = 0; k < NSTEP; ++k) acc[k] = make_float2(0.f, 0.f);

  float2 va[8], vb[8];
  int4 sa0, sa1, sb0, sb1;

#define LOADS(S0, S1, base)                         \
  { S0 = *(const int4*)&s_step[(base)];             \
    S1 = *(const int4*)&s_step[(base) + 4]; }

#define LOADG(dst, base)                                        \
  _Pragma("unroll")                                             \
  for (int u = 0; u < 8; ++u) dst[u] = hp[(size_t)((base) + u) * ROW2];

#define ACC1(V, SS)                                                            \
  { const int s_ = __builtin_amdgcn_readfirstlane(SS);                         \
    switch (s_) {                                                              \
      case 0:  acc[0].x  += V.x; acc[0].y  += V.y; break;                      \
      case 1:  acc[1].x  += V.x; acc[1].y  += V.y; break;                      \
      case 2:  acc[2].x  += V.x; acc[2].y  += V.y; break;                      \
      case 3:  acc[3].x  += V.x; acc[3].y  += V.y; break;                      \
      case 4:  acc[4].x  += V.x; acc[4].y  += V.y; break;                      \
      case 5:  acc[5].x  += V.x; acc[5].y  += V.y; break;                      \
      case 6:  acc[6].x  += V.x; acc[6].y  += V.y; break;                      \
      case 7:  acc[7].x  += V.x; acc[7].y  += V.y; break;                      \
      case 8:  acc[8].x  += V.x; acc[8].y  += V.y; break;                      \
      case 9:  acc[9].x  += V.x; acc[9].y  += V.y; break;                      \
      case 10: acc[10].x += V.x; acc[10].y += V.y; break;                      \
      case 11: acc[11].x += V.x; acc[11].y += V.y; break;                      \
      case 12: acc[12].x += V.x; acc[12].y += V.y; break;                      \
      case 13: acc[13].x += V.x; acc[13].y += V.y; break;                      \
      case 14: acc[14].x += V.x; acc[14].y += V.y; break;                      \
      case 15: acc[15].x += V.x; acc[15].y += V.y; break;                      \
    } }

#define PROC(src, S0, S1)                                                      \
  ACC1(src[0], S0.x) ACC1(src[1], S0.y) ACC1(src[2], S0.z) ACC1(src[3], S0.w) \
  ACC1(src[4], S1.x) ACC1(src[5], S1.y) ACC1(src[6], S1.z) ACC1(src[7], S1.w)

  LOADS(sa0, sa1, 0)
  LOADG(va, 0)
  for (int t = 0; t < TCHUNK; t += 16) {
    LOADS(sb0, sb1, t + 8)
    LOADG(vb, t + 8)
    PROC(va, sa0, sa1)
    if (t + 16 < TCHUNK) { LOADS(sa0, sa1, t + 16) LOADG(va, t + 16) }
    PROC(vb, sb0, sb1)
  }
#undef LOADS
#undef LOADG
#undef ACC1
#undef PROC

  float2* op = (float2*)part + (size_t)z * (PART_FLOATS / 2) +
               ((size_t)bn * NSTEP) * ROW2 + col2;
#pragma unroll
  for (int k = 0; k < NSTEP; ++k) op[(size_t)k * ROW2] = acc[k];
}

// ---------------- Kernel 1b: reduce TSPLIT partials -> ssum ----------------
__global__ __launch_bounds__(256) void k_reduce(const float4* __restrict__ part,
                                                float4* __restrict__ ssum) {
  const size_t i = (size_t)blockIdx.x * 256 + threadIdx.x;   // < PART_FLOATS/4
  const size_t slice = PART_FLOATS / 4;
  float4 s = part[i];
#pragma unroll
  for (int zz = 1; zz < TSPLIT; ++zz) {
    const float4 v = part[(size_t)zz * slice + i];
    s.x += v.x; s.y += v.y; s.z += v.z; s.w += v.w;
  }
  ssum[i] = s;
}

// ---------------- Kernel 2: per-(b,n) cosine weights -> text_logits ----------------
__global__ __launch_bounds__(1024) void k_bn(const float* __restrict__ pol,
                                             const float* __restrict__ refp,
                                             const int* __restrict__ step,
                                             const float* __restrict__ ssum,
                                             float* __restrict__ text_logits) {
  const int bn  = blockIdx.x;
  const int b   = bn >> 3;
  const int bn0 = b << 3;
  const int wave = threadIdx.x >> 6;   // 0..15 == segment
  const int lane = threadIdx.x & 63;

  __shared__ float cnt[NSTEP], cnt0[NSTEP], lsum[NSTEP], wgt[NSTEP];
  if (threadIdx.x < NSTEP) {
    cnt[threadIdx.x] = 0.f; cnt0[threadIdx.x] = 0.f; lsum[threadIdx.x] = 0.f;
  }
  __syncthreads();

  for (int t = threadIdx.x; t < TT; t += 1024) {
    const int s = step[bn * TT + t];
    atomicAdd(&cnt[s], 1.f);
    atomicAdd(&lsum[s], pol[bn * TT + t] - refp[bn * TT + t]);
    const int s0 = step[bn0 * TT + t];
    atomicAdd(&cnt0[s0], 1.f);
  }
  __syncthreads();

  const int s = wave;
  const float c  = fmaxf(cnt[s],  1.f);
  const float c0 = fmaxf(cnt0[s], 1.f);
  const float ic  = 1.f / c;
  const float ic0 = 1.f / c0;
  const float4* p  = (const float4*)(ssum + ((size_t)bn  * NSTEP + s) * HH);
  const float4* p0 = (const float4*)(ssum + ((size_t)bn0 * NSTEP + s) * HH);

  float dot = 0.f, nn = 0.f, rr = 0.f;
#pragma unroll
  for (int i = 0; i < 8; ++i) {
    const float4 a4 = p[lane + i * 64];
    const float4 r4 = p0[lane + i * 64];
    const float ax = a4.x * ic, ay = a4.y * ic, az = a4.z * ic, aw = a4.w * ic;
    const float rx = r4.x * ic0, ry = r4.y * ic0, rz = r4.z * ic0, rw = r4.w * ic0;
    dot += ax * rx + ay * ry + az * rz + aw * rw;
    nn  += ax * ax + ay * ay + az * az + aw * aw;
    rr  += rx * rx + ry * ry + rz * rz + rw * rw;
  }
#pragma unroll
  for (int off = 32; off > 0; off >>= 1) {
    dot += __shfl_down(dot, off);
    nn  += __shfl_down(nn,  off);
    rr  += __shfl_down(rr,  off);
  }
  if (lane == 0) {
    const float nrm = fmaxf(sqrtf(nn), EPSF);
    const float rn  = fmaxf(sqrtf(rr), EPSF);
    const float cosv = dot / (nrm * rn);
    const bool valid = (cnt[s] > 0.f) && (cnt0[s] > 0.f) && (s >= 1);
    wgt[s] = valid ? (cosv + 1.f) : 0.f;
  }
  __syncthreads();

  if (threadIdx.x == 0) {
    float wsum = 0.f, tw = 0.f;
#pragma unroll
    for (int k = 0; k < NSTEP; ++k) {
      const float w = wgt[k];
      wsum += w * (lsum[k] / fmaxf(cnt[k], 1.f));
      tw   += w;
    }
    text_logits[bn] = (tw > 0.f) ? (wsum / fmaxf(tw, EPSF)) : 0.f;
  }
}

// ---------------- Kernel 3: LambdaRank loss + reward means ----------------
__device__ inline float softplus_f(float x) {
  return fmaxf(x, 0.f) + log1pf(expf(-fabsf(x)));
}

__global__ __launch_bounds__(256) void k_final(const float* __restrict__ pol,
                                               const float* __restrict__ refp,
                                               const float* __restrict__ labels,
                                               const float* __restrict__ text_logits,
                                               float* __restrict__ out) {
  const int which = blockIdx.x;
  const int wave = threadIdx.x >> 6;
  const int lane = threadIdx.x & 63;
  __shared__ float red[4];

  if (which == 0) {
    float part = 0.f;
    if (threadIdx.x < 64) {
      const int b = threadIdx.x >> 3, i = threadIdx.x & 7;
      const float pi = text_logits[b * 8 + i];
      const float li = labels[b * 8 + i];
#pragma unroll
      for (int j = 0; j < 8; ++j) {
        const float ld = li - labels[b * 8 + j];
        const float sg = (ld > 0.f) ? 1.f : ((ld < 0.f) ? -1.f : 0.f);
        const float z  = (pi - text_logits[b * 8 + j]) * sg;
        part += softplus_f(-z);
      }
    }
    if (wave == 0) {
#pragma unroll
      for (int off = 32; off > 0; off >>= 1) part += __shfl_down(part, off);
      if (lane == 0) {
        const float lr = part / (56.f * 8.f);
        out[0] = softplus_f(-BETA * lr);
      }
    }
  } else {
    const int n = (which == 1) ? 0 : 7;
    float s = 0.f;
    for (int i = threadIdx.x; i < 8 * TT; i += 256) {
      const int b = i >> 11, t = i & (TT - 1);
      const size_t idx = ((size_t)(b * 8 + n)) * TT + t;
      s += pol[idx] - refp[idx];
    }
#pragma unroll
    for (int off = 32; off > 0; off >>= 1) s += __shfl_down(s, off);
    if (lane == 0) red[wave] = s;
    __syncthreads();
    if (threadIdx.x == 0)
      out[which] = (red[0] + red[1] + red[2] + red[3]) / (8.f * TT);
  }
}

extern "C" void kernel_launch(void* const* d_in, const int* in_sizes, int n_in,
                              void* d_out, int out_size, void* d_ws, size_t ws_size,
                              hipStream_t stream) {
  const float* pol    = (const float*)d_in[0];
  const float* refp   = (const float*)d_in[1];
  const float* hidden = (const float*)d_in[2];
  const int*   step   = (const int*)d_in[3];
  const float* labels = (const float*)d_in[4];
  float* out = (float*)d_out;

  float* part = (float*)d_ws;                                  // TSPLIT * 8 MB
  float* ssum = part + (size_t)TSPLIT * PART_FLOATS;           // 8 MB
  float* text_logits = ssum + PART_FLOATS;                     // 64 floats

  dim3 g1(4, 64, TSPLIT);
  k_segsum2<<<g1, 256, 0, stream>>>(hidden, step, (float2*)part);
  k_reduce<<<(int)(PART_FLOATS / 4 / 256), 256, 0, stream>>>((const float4*)part,
                                                             (float4*)ssum);
  k_bn<<<64, 1024, 0, stream>>>(pol, refp, step, ssum, text_logits);
  k_final<<<3, 256, 0, stream>>>(pol, refp, labels, text_logits, out);
}

// Round 7
// 238.794 us; speedup vs baseline: 1.4692x; 1.0524x over previous
//
#include <hip/hip_runtime.h>
#include <math.h>

#define TT 2048
#define HH 2048
#define NSTEP 16
#define EPSF 1e-8f
#define BETA 0.1f
#define TSPLIT 2
#define TCHUNK (TT / TSPLIT)                   // 1024
#define ROW2 (HH / 2)                          // 1024 float2 per row
#define PART_FLOATS ((size_t)64 * NSTEP * HH)  // floats per z-slice (8 MB)

// ---------------- Kernel 1: partial segment-sums, float2, T-split ----------------
// grid (4, 64, TSPLIT), block 256. Sequential row order (DRAM-friendly).
// Step values prefetched one 8-row group ahead as uniform int4 LDS reads.
__global__ __launch_bounds__(256, 4) void k_segsum2(const float* __restrict__ hidden,
                                                    const int* __restrict__ step,
                                                    float2* __restrict__ part) {
  const int bn   = blockIdx.y;
  const int z    = blockIdx.z;
  const int col2 = blockIdx.x * 256 + threadIdx.x;   // [0, 1024)
  const int t0   = z * TCHUNK;

  __shared__ int s_step[TCHUNK];
  for (int i = threadIdx.x; i < TCHUNK; i += 256) s_step[i] = step[bn * TT + t0 + i];
  __syncthreads();

  const float2* hp = (const float2*)hidden + (size_t)(bn * TT + t0) * ROW2 + col2;

  float2 acc[NSTEP];
#pragma unroll
  for (int k = 0; k < NSTEP; ++k) acc[k] = make_float2(0.f, 0.f);

  float2 va[8], vb[8];
  int4 sa0, sa1, sb0, sb1;

#define LOADS(S0, S1, base)                         \
  { S0 = *(const int4*)&s_step[(base)];             \
    S1 = *(const int4*)&s_step[(base) + 4]; }

#define LOADG(dst, base)                                        \
  _Pragma("unroll")                                             \
  for (int u = 0; u < 8; ++u) dst[u] = hp[(size_t)((base) + u) * ROW2];

#define ACC1(V, SS)                                                            \
  { const int s_ = __builtin_amdgcn_readfirstlane(SS);                         \
    switch (s_) {                                                              \
      case 0:  acc[0].x  += V.x; acc[0].y  += V.y; break;                      \
      case 1:  acc[1].x  += V.x; acc[1].y  += V.y; break;                      \
      case 2:  acc[2].x  += V.x; acc[2].y  += V.y; break;                      \
      case 3:  acc[3].x  += V.x; acc[3].y  += V.y; break;                      \
      case 4:  acc[4].x  += V.x; acc[4].y  += V.y; break;                      \
      case 5:  acc[5].x  += V.x; acc[5].y  += V.y; break;                      \
      case 6:  acc[6].x  += V.x; acc[6].y  += V.y; break;                      \
      case 7:  acc[7].x  += V.x; acc[7].y  += V.y; break;                      \
      case 8:  acc[8].x  += V.x; acc[8].y  += V.y; break;                      \
      case 9:  acc[9].x  += V.x; acc[9].y  += V.y; break;                      \
      case 10: acc[10].x += V.x; acc[10].y += V.y; break;                      \
      case 11: acc[11].x += V.x; acc[11].y += V.y; break;                      \
      case 12: acc[12].x += V.x; acc[12].y += V.y; break;                      \
      case 13: acc[13].x += V.x; acc[13].y += V.y; break;                      \
      case 14: acc[14].x += V.x; acc[14].y += V.y; break;                      \
      case 15: acc[15].x += V.x; acc[15].y += V.y; break;                      \
    } }

#define PROC(src, S0, S1)                                                      \
  ACC1(src[0], S0.x) ACC1(src[1], S0.y) ACC1(src[2], S0.z) ACC1(src[3], S0.w) \
  ACC1(src[4], S1.x) ACC1(src[5], S1.y) ACC1(src[6], S1.z) ACC1(src[7], S1.w)

  LOADS(sa0, sa1, 0)
  LOADG(va, 0)
  for (int t = 0; t < TCHUNK; t += 16) {
    LOADS(sb0, sb1, t + 8)
    LOADG(vb, t + 8)
    PROC(va, sa0, sa1)
    if (t + 16 < TCHUNK) { LOADS(sa0, sa1, t + 16) LOADG(va, t + 16) }
    PROC(vb, sb0, sb1)
  }
#undef LOADS
#undef LOADG
#undef ACC1
#undef PROC

  float2* op = (float2*)part + (size_t)z * (PART_FLOATS / 2) +
               ((size_t)bn * NSTEP) * ROW2 + col2;
#pragma unroll
  for (int k = 0; k < NSTEP; ++k) op[(size_t)k * ROW2] = acc[k];
}

// ---------------- Kernel 2: fused reduce + per-(b,n) cosine -> text_logits ----------------
// 64 blocks x 1024 threads. Phase A: per-wave LDS count arrays (no cross-wave
// atomic serialization). Phase B: wave s sums TSPLIT partial slices directly.
__global__ __launch_bounds__(1024) void k_bn(const float* __restrict__ pol,
                                             const float* __restrict__ refp,
                                             const int* __restrict__ step,
                                             const float* __restrict__ part,
                                             float* __restrict__ text_logits) {
  const int bn  = blockIdx.x;
  const int b   = bn >> 3;
  const int bn0 = b << 3;
  const int wave = threadIdx.x >> 6;   // 0..15 == segment
  const int lane = threadIdx.x & 63;

  __shared__ float cnt_w[16][NSTEP], lsum_w[16][NSTEP], cnt0_w[16][NSTEP];
  __shared__ float cnt[NSTEP], cnt0[NSTEP], lsum[NSTEP], wgt[NSTEP];

  if (lane < NSTEP) {
    cnt_w[wave][lane] = 0.f; lsum_w[wave][lane] = 0.f; cnt0_w[wave][lane] = 0.f;
  }
  __syncthreads();

  for (int t = threadIdx.x; t < TT; t += 1024) {
    const int s = step[bn * TT + t];
    atomicAdd(&cnt_w[wave][s], 1.f);
    atomicAdd(&lsum_w[wave][s], pol[bn * TT + t] - refp[bn * TT + t]);
    const int s0 = step[bn0 * TT + t];
    atomicAdd(&cnt0_w[wave][s0], 1.f);
  }
  __syncthreads();

  if (threadIdx.x < NSTEP) {
    float c = 0.f, l = 0.f, c0 = 0.f;
#pragma unroll
    for (int w = 0; w < 16; ++w) {
      c  += cnt_w[w][threadIdx.x];
      l  += lsum_w[w][threadIdx.x];
      c0 += cnt0_w[w][threadIdx.x];
    }
    cnt[threadIdx.x] = c; lsum[threadIdx.x] = l; cnt0[threadIdx.x] = c0;
  }
  __syncthreads();

  const int s = wave;
  const float c  = fmaxf(cnt[s],  1.f);
  const float c0 = fmaxf(cnt0[s], 1.f);
  const float ic  = 1.f / c;
  const float ic0 = 1.f / c0;
  const float4* po0 = (const float4*)(part + ((size_t)bn  * NSTEP + s) * HH);
  const float4* po1 = (const float4*)(part + PART_FLOATS + ((size_t)bn  * NSTEP + s) * HH);
  const float4* pr0 = (const float4*)(part + ((size_t)bn0 * NSTEP + s) * HH);
  const float4* pr1 = (const float4*)(part + PART_FLOATS + ((size_t)bn0 * NSTEP + s) * HH);

  float dot = 0.f, nn = 0.f, rr = 0.f;
#pragma unroll
  for (int i = 0; i < 8; ++i) {
    const int idx = lane + i * 64;
    const float4 a0 = po0[idx], a1 = po1[idx];
    const float4 r0 = pr0[idx], r1 = pr1[idx];
    const float ax = (a0.x + a1.x) * ic,  ay = (a0.y + a1.y) * ic;
    const float az = (a0.z + a1.z) * ic,  aw = (a0.w + a1.w) * ic;
    const float rx = (r0.x + r1.x) * ic0, ry = (r0.y + r1.y) * ic0;
    const float rz = (r0.z + r1.z) * ic0, rw = (r0.w + r1.w) * ic0;
    dot += ax * rx + ay * ry + az * rz + aw * rw;
    nn  += ax * ax + ay * ay + az * az + aw * aw;
    rr  += rx * rx + ry * ry + rz * rz + rw * rw;
  }
#pragma unroll
  for (int off = 32; off > 0; off >>= 1) {
    dot += __shfl_down(dot, off);
    nn  += __shfl_down(nn,  off);
    rr  += __shfl_down(rr,  off);
  }
  if (lane == 0) {
    const float nrm = fmaxf(sqrtf(nn), EPSF);
    const float rn  = fmaxf(sqrtf(rr), EPSF);
    const float cosv = dot / (nrm * rn);
    const bool valid = (cnt[s] > 0.f) && (cnt0[s] > 0.f) && (s >= 1);
    wgt[s] = valid ? (cosv + 1.f) : 0.f;
  }
  __syncthreads();

  if (threadIdx.x == 0) {
    float wsum = 0.f, tw = 0.f;
#pragma unroll
    for (int k = 0; k < NSTEP; ++k) {
      const float w = wgt[k];
      wsum += w * (lsum[k] / fmaxf(cnt[k], 1.f));
      tw   += w;
    }
    text_logits[bn] = (tw > 0.f) ? (wsum / fmaxf(tw, EPSF)) : 0.f;
  }
}

// ---------------- Kernel 3: LambdaRank loss + reward means ----------------
__device__ inline float softplus_f(float x) {
  return fmaxf(x, 0.f) + log1pf(expf(-fabsf(x)));
}

__global__ __launch_bounds__(256) void k_final(const float* __restrict__ pol,
                                               const float* __restrict__ refp,
                                               const float* __restrict__ labels,
                                               const float* __restrict__ text_logits,
                                               float* __restrict__ out) {
  const int which = blockIdx.x;
  const int wave = threadIdx.x >> 6;
  const int lane = threadIdx.x & 63;
  __shared__ float red[4];

  if (which == 0) {
    float part = 0.f;
    if (threadIdx.x < 64) {
      const int b = threadIdx.x >> 3, i = threadIdx.x & 7;
      const float pi = text_logits[b * 8 + i];
      const float li = labels[b * 8 + i];
#pragma unroll
      for (int j = 0; j < 8; ++j) {
        const float ld = li - labels[b * 8 + j];
        const float sg = (ld > 0.f) ? 1.f : ((ld < 0.f) ? -1.f : 0.f);
        const float z  = (pi - text_logits[b * 8 + j]) * sg;
        part += softplus_f(-z);
      }
    }
    if (wave == 0) {
#pragma unroll
      for (int off = 32; off > 0; off >>= 1) part += __shfl_down(part, off);
      if (lane == 0) {
        const float lr = part / (56.f * 8.f);
        out[0] = softplus_f(-BETA * lr);
      }
    }
  } else {
    const int n = (which == 1) ? 0 : 7;
    float s = 0.f;
    for (int i = threadIdx.x; i < 8 * TT; i += 256) {
      const int b = i >> 11, t = i & (TT - 1);
      const size_t idx = ((size_t)(b * 8 + n)) * TT + t;
      s += pol[idx] - refp[idx];
    }
#pragma unroll
    for (int off = 32; off > 0; off >>= 1) s += __shfl_down(s, off);
    if (lane == 0) red[wave] = s;
    __syncthreads();
    if (threadIdx.x == 0)
      out[which] = (red[0] + red[1] + red[2] + red[3]) / (8.f * TT);
  }
}

extern "C" void kernel_launch(void* const* d_in, const int* in_sizes, int n_in,
                              void* d_out, int out_size, void* d_ws, size_t ws_size,
                              hipStream_t stream) {
  const float* pol    = (const float*)d_in[0];
  const float* refp   = (const float*)d_in[1];
  const float* hidden = (const float*)d_in[2];
  const int*   step   = (const int*)d_in[3];
  const float* labels = (const float*)d_in[4];
  float* out = (float*)d_out;

  float* part = (float*)d_ws;                                  // TSPLIT * 8 MB
  float* text_logits = part + (size_t)TSPLIT * PART_FLOATS;    // 64 floats

  dim3 g1(4, 64, TSPLIT);
  k_segsum2<<<g1, 256, 0, stream>>>(hidden, step, (float2*)part);
  k_bn<<<64, 1024, 0, stream>>>(pol, refp, step, part, text_logits);
  k_final<<<3, 256, 0, stream>>>(pol, refp, labels, text_logits, out);
}

// Round 9
// 215.043 us; speedup vs baseline: 1.6315x; 1.1104x over previous
//
#include <hip/hip_runtime.h>
#include <math.h>

#define TT 2048
#define HH 2048
#define NSTEP 16
#define EPSF 1e-8f
#define BETA 0.1f
#define TSPLIT 2
#define TCHUNK (TT / TSPLIT)                   // 1024
#define ROW2 (HH / 2)                          // 1024 float2 per row
#define PART_FLOATS ((size_t)64 * NSTEP * HH)  // floats per z-slice (8 MB)

typedef float f2v __attribute__((ext_vector_type(2)));

// ---------------- Kernel 1: partial segment-sums, float2, T-split ----------------
// grid (4, 64, TSPLIT), block 256. Sequential row order (DRAM-friendly).
// Step values prefetched one 8-row group ahead as uniform int4 LDS reads.
// hidden loads are nontemporal (single-pass stream, no cache allocation).
__global__ __launch_bounds__(256, 4) void k_segsum2(const float* __restrict__ hidden,
                                                    const int* __restrict__ step,
                                                    float2* __restrict__ part) {
  const int bn   = blockIdx.y;
  const int z    = blockIdx.z;
  const int col2 = blockIdx.x * 256 + threadIdx.x;   // [0, 1024)
  const int t0   = z * TCHUNK;

  __shared__ int s_step[TCHUNK];
  for (int i = threadIdx.x; i < TCHUNK; i += 256) s_step[i] = step[bn * TT + t0 + i];
  __syncthreads();

  const f2v* hp = (const f2v*)hidden + (size_t)(bn * TT + t0) * ROW2 + col2;

  float2 acc[NSTEP];
#pragma unroll
  for (int k = 0; k < NSTEP; ++k) acc[k] = make_float2(0.f, 0.f);

  f2v va[8], vb[8];
  int4 sa0, sa1, sb0, sb1;

#define LOADS(S0, S1, base)                         \
  { S0 = *(const int4*)&s_step[(base)];             \
    S1 = *(const int4*)&s_step[(base) + 4]; }

#define LOADG(dst, base)                                        \
  _Pragma("unroll")                                             \
  for (int u = 0; u < 8; ++u)                                   \
    dst[u] = __builtin_nontemporal_load(&hp[(size_t)((base) + u) * ROW2]);

#define ACC1(V, SS)                                                            \
  { const int s_ = __builtin_amdgcn_readfirstlane(SS);                         \
    switch (s_) {                                                              \
      case 0:  acc[0].x  += V.x; acc[0].y  += V.y; break;                      \
      case 1:  acc[1].x  += V.x; acc[1].y  += V.y; break;                      \
      case 2:  acc[2].x  += V.x; acc[2].y  += V.y; break;                      \
      case 3:  acc[3].x  += V.x; acc[3].y  += V.y; break;                      \
      case 4:  acc[4].x  += V.x; acc[4].y  += V.y; break;                      \
      case 5:  acc[5].x  += V.x; acc[5].y  += V.y; break;                      \
      case 6:  acc[6].x  += V.x; acc[6].y  += V.y; break;                      \
      case 7:  acc[7].x  += V.x; acc[7].y  += V.y; break;                      \
      case 8:  acc[8].x  += V.x; acc[8].y  += V.y; break;                      \
      case 9:  acc[9].x  += V.x; acc[9].y  += V.y; break;                      \
      case 10: acc[10].x += V.x; acc[10].y += V.y; break;                      \
      case 11: acc[11].x += V.x; acc[11].y += V.y; break;                      \
      case 12: acc[12].x += V.x; acc[12].y += V.y; break;                      \
      case 13: acc[13].x += V.x; acc[13].y += V.y; break;                      \
      case 14: acc[14].x += V.x; acc[14].y += V.y; break;                      \
      case 15: acc[15].x += V.x; acc[15].y += V.y; break;                      \
    } }

#define PROC(src, S0, S1)                                                      \
  ACC1(src[0], S0.x) ACC1(src[1], S0.y) ACC1(src[2], S0.z) ACC1(src[3], S0.w) \
  ACC1(src[4], S1.x) ACC1(src[5], S1.y) ACC1(src[6], S1.z) ACC1(src[7], S1.w)

  LOADS(sa0, sa1, 0)
  LOADG(va, 0)
  for (int t = 0; t < TCHUNK; t += 16) {
    LOADS(sb0, sb1, t + 8)
    LOADG(vb, t + 8)
    PROC(va, sa0, sa1)
    if (t + 16 < TCHUNK) { LOADS(sa0, sa1, t + 16) LOADG(va, t + 16) }
    PROC(vb, sb0, sb1)
  }
#undef LOADS
#undef LOADG
#undef ACC1
#undef PROC

  float2* op = (float2*)part + (size_t)z * (PART_FLOATS / 2) +
               ((size_t)bn * NSTEP) * ROW2 + col2;
#pragma unroll
  for (int k = 0; k < NSTEP; ++k) op[(size_t)k * ROW2] = acc[k];
}

// ---------------- Kernel 2: fused reduce + cosine + reward means ----------------
// 66 blocks x 1024 threads. Blocks 0..63: per-(b,n) pipeline -> text_logits.
// Blocks 64,65: chosen/rejected reward means (independent, run on idle CUs).
__global__ __launch_bounds__(1024) void k_bn(const float* __restrict__ pol,
                                             const float* __restrict__ refp,
                                             const int* __restrict__ step,
                                             const float* __restrict__ part,
                                             float* __restrict__ text_logits,
                                             float* __restrict__ out) {
  const int wave = threadIdx.x >> 6;
  const int lane = threadIdx.x & 63;

  if (blockIdx.x >= 64) {               // reward-mean blocks
    const int n = (blockIdx.x == 64) ? 0 : 7;
    __shared__ float red[16];
    const float4* p4 = (const float4*)pol;
    const float4* r4 = (const float4*)refp;
    float s = 0.f;
    for (int j = threadIdx.x; j < 4096; j += 1024) {   // 8*2048/4 float4s
      const int b = j >> 9, t4 = j & 511;
      const int idx = (b * 8 + n) * 512 + t4;
      const float4 a = p4[idx], r = r4[idx];
      s += (a.x - r.x) + (a.y - r.y) + (a.z - r.z) + (a.w - r.w);
    }
#pragma unroll
    for (int off = 32; off > 0; off >>= 1) s += __shfl_down(s, off);
    if (lane == 0) red[wave] = s;
    __syncthreads();
    if (threadIdx.x == 0) {
      float tot = 0.f;
#pragma unroll
      for (int w = 0; w < 16; ++w) tot += red[w];
      out[(blockIdx.x == 64) ? 1 : 2] = tot / (8.f * TT);
    }
    return;
  }

  const int bn  = blockIdx.x;
  const int b   = bn >> 3;
  const int bn0 = b << 3;

  __shared__ float cnt_w[16][NSTEP], lsum_w[16][NSTEP], cnt0_w[16][NSTEP];
  __shared__ float cnt[NSTEP], cnt0[NSTEP], lsum[NSTEP], wgt[NSTEP];

  if (lane < NSTEP) {
    cnt_w[wave][lane] = 0.f; lsum_w[wave][lane] = 0.f; cnt0_w[wave][lane] = 0.f;
  }
  __syncthreads();

  for (int t = threadIdx.x; t < TT; t += 1024) {
    const int s = step[bn * TT + t];
    atomicAdd(&cnt_w[wave][s], 1.f);
    atomicAdd(&lsum_w[wave][s], pol[bn * TT + t] - refp[bn * TT + t]);
    const int s0 = step[bn0 * TT + t];
    atomicAdd(&cnt0_w[wave][s0], 1.f);
  }
  __syncthreads();

  if (threadIdx.x < NSTEP) {
    float c = 0.f, l = 0.f, c0 = 0.f;
#pragma unroll
    for (int w = 0; w < 16; ++w) {
      c  += cnt_w[w][threadIdx.x];
      l  += lsum_w[w][threadIdx.x];
      c0 += cnt0_w[w][threadIdx.x];
    }
    cnt[threadIdx.x] = c; lsum[threadIdx.x] = l; cnt0[threadIdx.x] = c0;
  }
  __syncthreads();

  const int s = wave;
  const float c  = fmaxf(cnt[s],  1.f);
  const float c0 = fmaxf(cnt0[s], 1.f);
  const float ic  = 1.f / c;
  const float ic0 = 1.f / c0;
  const float4* po0 = (const float4*)(part + ((size_t)bn  * NSTEP + s) * HH);
  const float4* po1 = (const float4*)(part + PART_FLOATS + ((size_t)bn  * NSTEP + s) * HH);
  const float4* pr0 = (const float4*)(part + ((size_t)bn0 * NSTEP + s) * HH);
  const float4* pr1 = (const float4*)(part + PART_FLOATS + ((size_t)bn0 * NSTEP + s) * HH);

  float dot = 0.f, nn = 0.f, rr = 0.f;
#pragma unroll
  for (int i = 0; i < 8; ++i) {
    const int idx = lane + i * 64;
    const float4 a0 = po0[idx], a1 = po1[idx];
    const float4 r0 = pr0[idx], r1 = pr1[idx];
    const float ax = (a0.x + a1.x) * ic,  ay = (a0.y + a1.y) * ic;
    const float az = (a0.z + a1.z) * ic,  aw = (a0.w + a1.w) * ic;
    const float rx = (r0.x + r1.x) * ic0, ry = (r0.y + r1.y) * ic0;
    const float rz = (r0.z + r1.z) * ic0, rw = (r0.w + r1.w) * ic0;
    dot += ax * rx + ay * ry + az * rz + aw * rw;
    nn  += ax * ax + ay * ay + az * az + aw * aw;
    rr  += rx * rx + ry * ry + rz * rz + rw * rw;
  }
#pragma unroll
  for (int off = 32; off > 0; off >>= 1) {
    dot += __shfl_down(dot, off);
    nn  += __shfl_down(nn,  off);
    rr  += __shfl_down(rr,  off);
  }
  if (lane == 0) {
    const float nrm = fmaxf(sqrtf(nn), EPSF);
    const float rn  = fmaxf(sqrtf(rr), EPSF);
    const float cosv = dot / (nrm * rn);
    const bool valid = (cnt[s] > 0.f) && (cnt0[s] > 0.f) && (s >= 1);
    wgt[s] = valid ? (cosv + 1.f) : 0.f;
  }
  __syncthreads();

  if (threadIdx.x == 0) {
    float wsum = 0.f, tw = 0.f;
#pragma unroll
    for (int k = 0; k < NSTEP; ++k) {
      const float w = wgt[k];
      wsum += w * (lsum[k] / fmaxf(cnt[k], 1.f));
      tw   += w;
    }
    text_logits[bn] = (tw > 0.f) ? (wsum / fmaxf(tw, EPSF)) : 0.f;
  }
}

// ---------------- Kernel 3: LambdaRank loss only (1 block, 64 threads) ----------------
__device__ inline float softplus_f(float x) {
  return fmaxf(x, 0.f) + log1pf(expf(-fabsf(x)));
}

__global__ __launch_bounds__(64) void k_final(const float* __restrict__ labels,
                                              const float* __restrict__ text_logits,
                                              float* __restrict__ out) {
  const int lane = threadIdx.x;
  float part = 0.f;
  {
    const int b = lane >> 3, i = lane & 7;
    const float pi = text_logits[b * 8 + i];
    const float li = labels[b * 8 + i];
#pragma unroll
    for (int j = 0; j < 8; ++j) {
      const float ld = li - labels[b * 8 + j];
      const float sg = (ld > 0.f) ? 1.f : ((ld < 0.f) ? -1.f : 0.f);
      const float z  = (pi - text_logits[b * 8 + j]) * sg;
      part += softplus_f(-z);
    }
  }
#pragma unroll
  for (int off = 32; off > 0; off >>= 1) part += __shfl_down(part, off);
  if (lane == 0) {
    const float lr = part / (56.f * 8.f);
    out[0] = softplus_f(-BETA * lr);
  }
}

extern "C" void kernel_launch(void* const* d_in, const int* in_sizes, int n_in,
                              void* d_out, int out_size, void* d_ws, size_t ws_size,
                              hipStream_t stream) {
  const float* pol    = (const float*)d_in[0];
  const float* refp   = (const float*)d_in[1];
  const float* hidden = (const float*)d_in[2];
  const int*   step   = (const int*)d_in[3];
  const float* labels = (const float*)d_in[4];
  float* out = (float*)d_out;

  float* part = (float*)d_ws;                                  // TSPLIT * 8 MB
  float* text_logits = part + (size_t)TSPLIT * PART_FLOATS;    // 64 floats

  dim3 g1(4, 64, TSPLIT);
  k_segsum2<<<g1, 256, 0, stream>>>(hidden, step, (float2*)part);
  k_bn<<<66, 1024, 0, stream>>>(pol, refp, step, part, text_logits, out);
  k_final<<<1, 64, 0, stream>>>(labels, text_logits, out);
}

// Round 10
// 207.000 us; speedup vs baseline: 1.6949x; 1.0389x over previous
//
#include <hip/hip_runtime.h>
#include <math.h>

#define TT 2048
#define HH 2048
#define NSTEP 16
#define EPSF 1e-8f
#define BETA 0.1f
#define TSPLIT 4
#define TCHUNK (TT / TSPLIT)                   // 512 rows per block
#define ROW2 (HH / 2)                          // 1024 float2 per row
#define PART_FLOATS ((size_t)64 * NSTEP * HH)  // floats per z-slice (8 MB)

typedef float f2v __attribute__((ext_vector_type(2)));

// ---------------- Kernel 1: partial segment-sums ----------------
// grid (64 bn, TSPLIT z), block 1024. One block covers a FULL 8KB row per step
// -> each block streams a contiguous 4MB region (DRAM row-buffer friendly),
// 16 waves/CU. float2/thread, unroll-4 double buffer, NT loads, step values
// prefetched as uniform int4 reads (register-resident, no per-row LDS chain).
__global__ __launch_bounds__(1024, 4) void k_segsum2(const float* __restrict__ hidden,
                                                     const int* __restrict__ step,
                                                     float2* __restrict__ part) {
  const int bn   = blockIdx.x;
  const int z    = blockIdx.y;
  const int col2 = threadIdx.x;                // [0, 1024)
  const int t0   = z * TCHUNK;

  __shared__ int s_step[TCHUNK];
  if (threadIdx.x < TCHUNK) s_step[threadIdx.x] = step[bn * TT + t0 + threadIdx.x];
  __syncthreads();

  const f2v* hp = (const f2v*)hidden + (size_t)(bn * TT + t0) * ROW2 + col2;

  float2 acc[NSTEP];
#pragma unroll
  for (int k = 0; k < NSTEP; ++k) acc[k] = make_float2(0.f, 0.f);

  f2v va[4], vb[4];
  int4 sa, sb;

#define LOADS(S, base) { S = *(const int4*)&s_step[(base)]; }

#define LOADG(dst, base)                                        \
  _Pragma("unroll")                                             \
  for (int u = 0; u < 4; ++u)                                   \
    dst[u] = __builtin_nontemporal_load(&hp[(size_t)((base) + u) * ROW2]);

#define ACC1(V, SS)                                                            \
  { const int s_ = __builtin_amdgcn_readfirstlane(SS);                         \
    switch (s_) {                                                              \
      case 0:  acc[0].x  += V.x; acc[0].y  += V.y; break;                      \
      case 1:  acc[1].x  += V.x; acc[1].y  += V.y; break;                      \
      case 2:  acc[2].x  += V.x; acc[2].y  += V.y; break;                      \
      case 3:  acc[3].x  += V.x; acc[3].y  += V.y; break;                      \
      case 4:  acc[4].x  += V.x; acc[4].y  += V.y; break;                      \
      case 5:  acc[5].x  += V.x; acc[5].y  += V.y; break;                      \
      case 6:  acc[6].x  += V.x; acc[6].y  += V.y; break;                      \
      case 7:  acc[7].x  += V.x; acc[7].y  += V.y; break;                      \
      case 8:  acc[8].x  += V.x; acc[8].y  += V.y; break;                      \
      case 9:  acc[9].x  += V.x; acc[9].y  += V.y; break;                      \
      case 10: acc[10].x += V.x; acc[10].y += V.y; break;                      \
      case 11: acc[11].x += V.x; acc[11].y += V.y; break;                      \
      case 12: acc[12].x += V.x; acc[12].y += V.y; break;                      \
      case 13: acc[13].x += V.x; acc[13].y += V.y; break;                      \
      case 14: acc[14].x += V.x; acc[14].y += V.y; break;                      \
      case 15: acc[15].x += V.x; acc[15].y += V.y; break;                      \
    } }

#define PROC(src, S)                                                           \
  ACC1(src[0], S.x) ACC1(src[1], S.y) ACC1(src[2], S.z) ACC1(src[3], S.w)

  LOADS(sa, 0)
  LOADG(va, 0)
  for (int t = 0; t < TCHUNK; t += 8) {
    LOADS(sb, t + 4)
    LOADG(vb, t + 4)
    PROC(va, sa)
    if (t + 8 < TCHUNK) { LOADS(sa, t + 8) LOADG(va, t + 8) }
    PROC(vb, sb)
  }
#undef LOADS
#undef LOADG
#undef ACC1
#undef PROC

  float2* op = (float2*)part + (size_t)z * (PART_FLOATS / 2) +
               ((size_t)bn * NSTEP) * ROW2 + col2;
#pragma unroll
  for (int k = 0; k < NSTEP; ++k) op[(size_t)k * ROW2] = acc[k];
}

// ---------------- Kernel 2: fused reduce + cosine + reward means ----------------
// 66 blocks x 1024 threads. Blocks 0..63: per-(b,n) pipeline -> text_logits.
// Blocks 64,65: chosen/rejected reward means (independent, run on idle CUs).
__global__ __launch_bounds__(1024) void k_bn(const float* __restrict__ pol,
                                             const float* __restrict__ refp,
                                             const int* __restrict__ step,
                                             const float* __restrict__ part,
                                             float* __restrict__ text_logits,
                                             float* __restrict__ out) {
  const int wave = threadIdx.x >> 6;
  const int lane = threadIdx.x & 63;

  if (blockIdx.x >= 64) {               // reward-mean blocks
    const int n = (blockIdx.x == 64) ? 0 : 7;
    __shared__ float red[16];
    const float4* p4 = (const float4*)pol;
    const float4* r4 = (const float4*)refp;
    float s = 0.f;
    for (int j = threadIdx.x; j < 4096; j += 1024) {   // 8*2048/4 float4s
      const int b = j >> 9, t4 = j & 511;
      const int idx = (b * 8 + n) * 512 + t4;
      const float4 a = p4[idx], r = r4[idx];
      s += (a.x - r.x) + (a.y - r.y) + (a.z - r.z) + (a.w - r.w);
    }
#pragma unroll
    for (int off = 32; off > 0; off >>= 1) s += __shfl_down(s, off);
    if (lane == 0) red[wave] = s;
    __syncthreads();
    if (threadIdx.x == 0) {
      float tot = 0.f;
#pragma unroll
      for (int w = 0; w < 16; ++w) tot += red[w];
      out[(blockIdx.x == 64) ? 1 : 2] = tot / (8.f * TT);
    }
    return;
  }

  const int bn  = blockIdx.x;
  const int b   = bn >> 3;
  const int bn0 = b << 3;

  __shared__ float cnt_w[16][NSTEP], lsum_w[16][NSTEP], cnt0_w[16][NSTEP];
  __shared__ float cnt[NSTEP], cnt0[NSTEP], lsum[NSTEP], wgt[NSTEP];

  if (lane < NSTEP) {
    cnt_w[wave][lane] = 0.f; lsum_w[wave][lane] = 0.f; cnt0_w[wave][lane] = 0.f;
  }
  __syncthreads();

  for (int t = threadIdx.x; t < TT; t += 1024) {
    const int s = step[bn * TT + t];
    atomicAdd(&cnt_w[wave][s], 1.f);
    atomicAdd(&lsum_w[wave][s], pol[bn * TT + t] - refp[bn * TT + t]);
    const int s0 = step[bn0 * TT + t];
    atomicAdd(&cnt0_w[wave][s0], 1.f);
  }
  __syncthreads();

  if (threadIdx.x < NSTEP) {
    float c = 0.f, l = 0.f, c0 = 0.f;
#pragma unroll
    for (int w = 0; w < 16; ++w) {
      c  += cnt_w[w][threadIdx.x];
      l  += lsum_w[w][threadIdx.x];
      c0 += cnt0_w[w][threadIdx.x];
    }
    cnt[threadIdx.x] = c; lsum[threadIdx.x] = l; cnt0[threadIdx.x] = c0;
  }
  __syncthreads();

  const int s = wave;
  const float c  = fmaxf(cnt[s],  1.f);
  const float c0 = fmaxf(cnt0[s], 1.f);
  const float ic  = 1.f / c;
  const float ic0 = 1.f / c0;
  const size_t offA = ((size_t)bn  * NSTEP + s) * HH;
  const size_t offR = ((size_t)bn0 * NSTEP + s) * HH;

  float dot = 0.f, nn = 0.f, rr = 0.f;
#pragma unroll
  for (int i = 0; i < 8; ++i) {
    const int idx = lane + i * 64;
    float ax = 0.f, ay = 0.f, az = 0.f, aw = 0.f;
    float rx = 0.f, ry = 0.f, rz = 0.f, rw = 0.f;
#pragma unroll
    for (int zz = 0; zz < TSPLIT; ++zz) {
      const float4 a = ((const float4*)(part + (size_t)zz * PART_FLOATS + offA))[idx];
      const float4 r = ((const float4*)(part + (size_t)zz * PART_FLOATS + offR))[idx];
      ax += a.x; ay += a.y; az += a.z; aw += a.w;
      rx += r.x; ry += r.y; rz += r.z; rw += r.w;
    }
    ax *= ic;  ay *= ic;  az *= ic;  aw *= ic;
    rx *= ic0; ry *= ic0; rz *= ic0; rw *= ic0;
    dot += ax * rx + ay * ry + az * rz + aw * rw;
    nn  += ax * ax + ay * ay + az * az + aw * aw;
    rr  += rx * rx + ry * ry + rz * rz + rw * rw;
  }
#pragma unroll
  for (int off = 32; off > 0; off >>= 1) {
    dot += __shfl_down(dot, off);
    nn  += __shfl_down(nn,  off);
    rr  += __shfl_down(rr,  off);
  }
  if (lane == 0) {
    const float nrm = fmaxf(sqrtf(nn), EPSF);
    const float rn  = fmaxf(sqrtf(rr), EPSF);
    const float cosv = dot / (nrm * rn);
    const bool valid = (cnt[s] > 0.f) && (cnt0[s] > 0.f) && (s >= 1);
    wgt[s] = valid ? (cosv + 1.f) : 0.f;
  }
  __syncthreads();

  if (threadIdx.x == 0) {
    float wsum = 0.f, tw = 0.f;
#pragma unroll
    for (int k = 0; k < NSTEP; ++k) {
      const float w = wgt[k];
      wsum += w * (lsum[k] / fmaxf(cnt[k], 1.f));
      tw   += w;
    }
    text_logits[bn] = (tw > 0.f) ? (wsum / fmaxf(tw, EPSF)) : 0.f;
  }
}

// ---------------- Kernel 3: LambdaRank loss only (1 block, 64 threads) ----------------
__device__ inline float softplus_f(float x) {
  return fmaxf(x, 0.f) + log1pf(expf(-fabsf(x)));
}

__global__ __launch_bounds__(64) void k_final(const float* __restrict__ labels,
                                              const float* __restrict__ text_logits,
                                              float* __restrict__ out) {
  const int lane = threadIdx.x;
  float part = 0.f;
  {
    const int b = lane >> 3, i = lane & 7;
    const float pi = text_logits[b * 8 + i];
    const float li = labels[b * 8 + i];
#pragma unroll
    for (int j = 0; j < 8; ++j) {
      const float ld = li - labels[b * 8 + j];
      const float sg = (ld > 0.f) ? 1.f : ((ld < 0.f) ? -1.f : 0.f);
      const float z  = (pi - text_logits[b * 8 + j]) * sg;
      part += softplus_f(-z);
    }
  }
#pragma unroll
  for (int off = 32; off > 0; off >>= 1) part += __shfl_down(part, off);
  if (lane == 0) {
    const float lr = part / (56.f * 8.f);
    out[0] = softplus_f(-BETA * lr);
  }
}

extern "C" void kernel_launch(void* const* d_in, const int* in_sizes, int n_in,
                              void* d_out, int out_size, void* d_ws, size_t ws_size,
                              hipStream_t stream) {
  const float* pol    = (const float*)d_in[0];
  const float* refp   = (const float*)d_in[1];
  const float* hidden = (const float*)d_in[2];
  const int*   step   = (const int*)d_in[3];
  const float* labels = (const float*)d_in[4];
  float* out = (float*)d_out;

  float* part = (float*)d_ws;                                  // TSPLIT * 8 MB
  float* text_logits = part + (size_t)TSPLIT * PART_FLOATS;    // 64 floats

  dim3 g1(64, TSPLIT);
  k_segsum2<<<g1, 1024, 0, stream>>>(hidden, step, (float2*)part);
  k_bn<<<66, 1024, 0, stream>>>(pol, refp, step, part, text_logits, out);
  k_final<<<1, 64, 0, stream>>>(labels, text_logits, out);
}